// Round 7
// baseline (231.474 us; speedup 1.0000x reference)
//
#include <hip/hip_runtime.h>

#define B   64
#define K   512
#define C   4
#define NL  5
#define NCH 64           // chunks for layers 2..5 (8 rows each, one WAVE each)
#define NCH1 128         // chunks for fused layer 1 (4 rows each)
#define BK  (B*K)

typedef _Float16 half_t;
typedef _Float16 half8 __attribute__((ext_vector_type(8)));
typedef float    f4    __attribute__((ext_vector_type(4)));

// ---------------------------------------------------------------------------
// Fused precompute + LAYER 1. Block = 2048 consecutive elements = 4 complete
// rows of one batch; wave w owns row, lane owns 8 consecutive cols.
//   - Habs2 = re^2+im^2 -> fp16 habs (L3-resident for layers 2..5)
//   - dabs2 diag extraction (in-wave fp32 diag via shuffle for layer 1)
//   - xsq fragment computed directly from vre/vim (no k_init dispatch)
//   - layer-1 phase 1: cov row-dot (fp32), u/w algebra, vtilde
//   - layer-1 phase 2: fragment * ulvec, 4-wave LDS combine, ulpart write
// h_re/h_im read ONCE (NT); habs never re-read for layer 1.
// ---------------------------------------------------------------------------
__global__ __launch_bounds__(256) void k_pre_l1(const float* __restrict__ hre,
                                                const float* __restrict__ him,
                                                const float* __restrict__ vre,
                                                const float* __restrict__ vim,
                                                const float* __restrict__ noise,
                                                half_t* __restrict__ habs,
                                                float* __restrict__ dabs2,
                                                float2* __restrict__ vtilde,
                                                float* __restrict__ ulpart) {
    int tid  = threadIdx.x;
    int lane = tid & 63;
    int wv   = tid >> 6;
    size_t base = (size_t)blockIdx.x * 2048 + (size_t)tid * 8;
    size_t b    = base >> 18;                   // batch
    int    j    = (int)((base >> 9) & (K - 1)); // row (wave-uniform)
    int    jc   = blockIdx.x & (NCH1 - 1);      // 4-row chunk index

    const f4* r4 = (const f4*)(hre + base);
    const f4* i4 = (const f4*)(him + base);
    f4 r0 = __builtin_nontemporal_load(r4);
    f4 r1 = __builtin_nontemporal_load(r4 + 1);
    f4 i0 = __builtin_nontemporal_load(i4);
    f4 i1 = __builtin_nontemporal_load(i4 + 1);

    // xsq for this lane's 8 columns, from vre/vim (128 KB arrays, L2/L3-hit)
    const f4* vr4 = (const f4*)(vre + b * K + lane * 8);
    const f4* vi4 = (const f4*)(vim + b * K + lane * 8);
    f4 va0 = vr4[0], va1 = vr4[1], vb0 = vi4[0], vb1 = vi4[1];
    float xs[8];
    xs[0] = va0.x * va0.x + vb0.x * vb0.x;
    xs[1] = va0.y * va0.y + vb0.y * vb0.y;
    xs[2] = va0.z * va0.z + vb0.z * vb0.z;
    xs[3] = va0.w * va0.w + vb0.w * vb0.w;
    xs[4] = va1.x * va1.x + vb1.x * vb1.x;
    xs[5] = va1.y * va1.y + vb1.y * vb1.y;
    xs[6] = va1.z * va1.z + vb1.z * vb1.z;
    xs[7] = va1.w * va1.w + vb1.w * vb1.w;

    float s[8];
    s[0] = r0.x * r0.x + i0.x * i0.x;
    s[1] = r0.y * r0.y + i0.y * i0.y;
    s[2] = r0.z * r0.z + i0.z * i0.z;
    s[3] = r0.w * r0.w + i0.w * i0.w;
    s[4] = r1.x * r1.x + i1.x * i1.x;
    s[5] = r1.y * r1.y + i1.y * i1.y;
    s[6] = r1.z * r1.z + i1.z * i1.z;
    s[7] = r1.w * r1.w + i1.w * i1.w;

    half8 h;
#pragma unroll
    for (int q = 0; q < 8; ++q) h[q] = (_Float16)s[q];
    *(half8*)(habs + base) = h;

    // fp32 diagonal |H_jj|^2 for this row: lane j>>3 holds it
    float cand = s[j & 7];
    float d2   = __shfl(cand, j >> 3, 64);
    float xsqj = __shfl(xs[j & 7], j >> 3, 64);
    if (lane == (j >> 3)) dabs2[b * K + j] = cand;

    // ---- layer-1 phase 1: cov dot ----
    float acc = s[0] * xs[0] + s[1] * xs[1] + s[2] * xs[2] + s[3] * xs[3] +
                s[4] * xs[4] + s[5] * xs[5] + s[6] * xs[6] + s[7] * xs[7];
#pragma unroll
    for (int off = 32; off; off >>= 1) acc += __shfl_xor(acc, off, 64);

    int bj = (int)(b * K) + j;
    float ulv;
    if (lane == 0) {
        float cov = acc + noise[bj];
        float A   = d2 * xsqj;
        float w   = cov / (cov - A);
        float sc  = d2 * w / cov;
        vtilde[bj] = make_float2(sc * vre[bj], sc * vim[bj]);
        ulv = A * w / (cov * cov);
    }
    ulv = __shfl(ulv, 0, 64);

    // ---- layer-1 phase 2: transposed-matvec partial for this 4-row chunk ----
    __shared__ float part[4][K];
    float* pw = &part[wv][lane * 8];
#pragma unroll
    for (int q = 0; q < 8; ++q) pw[q] = s[q] * ulv;
    __syncthreads();

    int c = tid * 2;
    float s0 = part[0][c]     + part[1][c]     + part[2][c]     + part[3][c];
    float s1 = part[0][c + 1] + part[1][c + 1] + part[2][c + 1] + part[3][c + 1];
    ((float2*)(ulpart + ((size_t)jc * B + b) * K))[tid] = make_float2(s0, s1);
}

// ---------------------------------------------------------------------------
// Layers 2..5: fused cov + transposed matvec, ONE WAVE per 8-row chunk.
// No LDS, no barriers — waves fully independent. Lanes 0-7 do the per-row
// algebra in parallel; 8 shuffle broadcasts feed the register combine.
// Grid: B*NCH/4 = 1024 blocks of 256 (4 independent waves each).
// ---------------------------------------------------------------------------
__global__ __launch_bounds__(256) void k_layer(const half_t* __restrict__ habs,
                                               const float* __restrict__ xsq,
                                               const float* __restrict__ noise,
                                               const float* __restrict__ dabs2,
                                               const float2* __restrict__ vstate,
                                               float2* __restrict__ vtilde,
                                               float* __restrict__ ulpart) {
    int lane = threadIdx.x & 63;
    int wv   = threadIdx.x >> 6;
    int task = blockIdx.x * 4 + wv;       // B*NCH tasks
    int b    = task >> 6;                 // / NCH
    int jc   = task & (NCH - 1);
    int j0   = jc * 8;

    const f4* x4 = (const f4*)(xsq + b * K);
    f4 xa = x4[lane * 2];
    f4 xb = x4[lane * 2 + 1];

    half8 h[8];
    const half8* rp = (const half8*)(habs + ((size_t)b * K + j0) * K);
#pragma unroll
    for (int r = 0; r < 8; ++r) h[r] = rp[r * (K / 8) + lane];

    float rs[8];
#pragma unroll
    for (int r = 0; r < 8; ++r) {
        float acc = (float)h[r][0] * xa.x + (float)h[r][1] * xa.y +
                    (float)h[r][2] * xa.z + (float)h[r][3] * xa.w +
                    (float)h[r][4] * xb.x + (float)h[r][5] * xb.y +
                    (float)h[r][6] * xb.z + (float)h[r][7] * xb.w;
#pragma unroll
        for (int off = 32; off; off >>= 1) acc += __shfl_xor(acc, off, 64);
        rs[r] = acc;                       // all lanes hold row sum r
    }

    // lanes 0-7: per-row u/w algebra in parallel
    float rsel = (lane < 4)
        ? ((lane < 2) ? ((lane == 0) ? rs[0] : rs[1])
                      : ((lane == 2) ? rs[2] : rs[3]))
        : ((lane < 6) ? ((lane == 4) ? rs[4] : rs[5])
                      : ((lane == 6) ? rs[6] : rs[7]));
    float ulv_mine = 0.f;
    if (lane < 8) {
        int bj    = b * K + j0 + lane;
        float cov = rsel + noise[bj];
        float A   = dabs2[bj] * xsq[bj];
        float w   = cov / (cov - A);
        float sc  = dabs2[bj] * w / cov;
        float2 vv = vstate[bj];
        vtilde[bj] = make_float2(sc * vv.x, sc * vv.y);
        ulv_mine = A * w / (cov * cov);
    }
    float u[8];
#pragma unroll
    for (int r = 0; r < 8; ++r) u[r] = __shfl(ulv_mine, r, 64);

    // register-only transposed-matvec partial for this chunk
    float acc[8] = {0.f, 0.f, 0.f, 0.f, 0.f, 0.f, 0.f, 0.f};
#pragma unroll
    for (int r = 0; r < 8; ++r)
#pragma unroll
        for (int q = 0; q < 8; ++q) acc[q] += (float)h[r][q] * u[r];

    float* outp = ulpart + ((size_t)jc * B + b) * K + lane * 8;
    ((float4*)outp)[0] = make_float4(acc[0], acc[1], acc[2], acc[3]);
    ((float4*)outp)[1] = make_float4(acc[4], acc[5], acc[6], acc[7]);
}

// ---------------------------------------------------------------------------
// Finish: sum NCHUNKS coalesced partial streams, mu/ula, ar/dl mix, CReLU,
// rc recombine, power correction; write new state + layer output.
// ---------------------------------------------------------------------------
template <int NCHUNKS>
__global__ __launch_bounds__(128) void k_fin(const float* __restrict__ ulpart,
                                             const float2* __restrict__ vtilde,
                                             const float* __restrict__ maxpow,
                                             const float* __restrict__ ar_re,
                                             const float* __restrict__ ar_im,
                                             const float* __restrict__ dl_re,
                                             const float* __restrict__ dl_im,
                                             const float* __restrict__ rc_re,
                                             const float* __restrict__ rc_im,
                                             float2* __restrict__ vstate,
                                             float* __restrict__ xsq,
                                             float* __restrict__ out) {
    int t = blockIdx.x * blockDim.x + threadIdx.x;
    float ul = 0.f;
#pragma unroll 16
    for (int jc = 0; jc < NCHUNKS; ++jc) ul += ulpart[(size_t)jc * BK + t];

    float2 vt = vtilde[t];
    float  p  = maxpow[t];
    float avt = sqrtf(vt.x * vt.x + vt.y * vt.y);
    float mu  = fmaxf(avt / sqrtf(p) - ul, 0.f);
    float ula = ul + mu;
    float inv = 1.f / ula;

    float ax = 0.f, ay = 0.f;
#pragma unroll
    for (int c = 0; c < C; ++c) {
        float gre = ar_re[c] * inv + dl_re[c];
        float gim = ar_im[c] * inv + dl_im[c];
        float zre = vt.x * gre - vt.y * gim;   // vt * g
        float zim = vt.x * gim + vt.y * gre;
        zre = fmaxf(zre, 0.f);                 // CReLU
        zim = fmaxf(zim, 0.f);
        ax += zre * rc_re[c] - zim * rc_im[c]; // += z * rc
        ay += zre * rc_im[c] + zim * rc_re[c];
    }
    float n2   = ax * ax + ay * ay;
    float cur  = fmaxf(p, n2);
    float corr = fminf(sqrtf(p / cur), 1.f);
    ax *= corr;
    ay *= corr;
    vstate[t] = make_float2(ax, ay);
    xsq[t]    = ax * ax + ay * ay;
    out[2 * t]     = ax;
    out[2 * t + 1] = ay;
}

// ---------------------------------------------------------------------------
extern "C" void kernel_launch(void* const* d_in, const int* in_sizes, int n_in,
                              void* d_out, int out_size, void* d_ws, size_t ws_size,
                              hipStream_t stream) {
    const float* hre   = (const float*)d_in[0];
    const float* him   = (const float*)d_in[1];
    const float* noise = (const float*)d_in[2];
    const float* mp    = (const float*)d_in[3];
    const float* vre   = (const float*)d_in[4];
    const float* vim   = (const float*)d_in[5];
    const float* ar_re = (const float*)d_in[6];
    const float* ar_im = (const float*)d_in[7];
    const float* dl_re = (const float*)d_in[8];
    const float* dl_im = (const float*)d_in[9];
    const float* rc_re = (const float*)d_in[10];
    const float* rc_im = (const float*)d_in[11];
    float* out = (float*)d_out;

    char*   ws     = (char*)d_ws;
    size_t  off    = 0;
    half_t* habs   = (half_t*)(ws + off); off += (size_t)BK * K * 2;   // 33.5 MB
    float*  dabs2  = (float*) (ws + off); off += (size_t)BK * 4;
    float2* vstate = (float2*)(ws + off); off += (size_t)BK * 8;
    float*  xsq    = (float*) (ws + off); off += (size_t)BK * 4;
    float2* vtilde = (float2*)(ws + off); off += (size_t)BK * 8;
    float*  ulpart = (float*) (ws + off); off += (size_t)NCH1 * BK * 4; // 16.8 MB

    // 16.78M elems / 8 per thread / 256 per block = 8192 blocks
    k_pre_l1<<<(size_t)BK * K / 8 / 256, 256, 0, stream>>>(hre, him, vre, vim,
                                                           noise, habs, dabs2,
                                                           vtilde, ulpart);
    k_fin<NCH1><<<BK / 128, 128, 0, stream>>>(ulpart, vtilde, mp,
                                              ar_re, ar_im, dl_re, dl_im,
                                              rc_re, rc_im, vstate, xsq, out);

    for (int l = 1; l < NL; ++l) {
        k_layer<<<B * NCH / 4, 256, 0, stream>>>(habs, xsq, noise, dabs2,
                                                 vstate, vtilde, ulpart);
        k_fin<NCH><<<BK / 128, 128, 0, stream>>>(ulpart, vtilde, mp,
                                                 ar_re, ar_im, dl_re, dl_im,
                                                 rc_re, rc_im, vstate, xsq,
                                                 out + (size_t)l * BK * 2);
    }
}

// Round 8
// 223.371 us; speedup vs baseline: 1.0363x; 1.0363x over previous
//
#include <hip/hip_runtime.h>

#define B   64
#define K   512
#define C   4
#define NL  5
#define BK  (B*K)
#define PS  (K + 4)      // padded LDS row stride (breaks 2KB bank alignment)

typedef _Float16 half_t;
typedef _Float16 half8 __attribute__((ext_vector_type(8)));
typedef float    f4    __attribute__((ext_vector_type(8/2)));

// ---------------------------------------------------------------------------
// Fused precompute + LAYER 1. Block = 8192 consecutive elements = 16 complete
// rows of one batch (1024 threads, 16 waves; wave = one row; lane = 8 cols).
//   - Habs2 = re^2+im^2 -> fp16 habs (L3-resident for layers 2..5)
//   - dabs2 diag (in-wave via shuffle), xsq from vre/vim directly
//   - layer-1 cov row-dot + u/w algebra -> vtilde(vt_a)
//   - transposed-matvec partial for 16 rows, LDS-combined, ONE atomicAdd per
//     column into dense ul0[b,k] (1M atomics total, 32-way contention)
// h_re/h_im read ONCE (NT). No ulpart buffer, no k_fin<128> dispatch.
// ---------------------------------------------------------------------------
__global__ __launch_bounds__(1024) void k_pre_l1(const float* __restrict__ hre,
                                                 const float* __restrict__ him,
                                                 const float* __restrict__ vre,
                                                 const float* __restrict__ vim,
                                                 const float* __restrict__ noise,
                                                 half_t* __restrict__ habs,
                                                 float* __restrict__ dabs2,
                                                 float2* __restrict__ vt_out,
                                                 float* __restrict__ ul0) {
    int tid  = threadIdx.x;
    int lane = tid & 63;
    int wv   = tid >> 6;                        // 0..15 = row within block
    size_t base = (size_t)blockIdx.x * 8192 + (size_t)tid * 8;
    size_t b    = base >> 18;                   // batch (block-uniform)
    int    j    = (int)((base >> 9) & (K - 1)); // row (wave-uniform)

    const f4* r4 = (const f4*)(hre + base);
    const f4* i4 = (const f4*)(him + base);
    f4 r0 = __builtin_nontemporal_load(r4);
    f4 r1 = __builtin_nontemporal_load(r4 + 1);
    f4 i0 = __builtin_nontemporal_load(i4);
    f4 i1 = __builtin_nontemporal_load(i4 + 1);

    // xsq for this lane's 8 columns from vre/vim (512 B/row, L1/L2-hit)
    const f4* vr4 = (const f4*)(vre + b * K + lane * 8);
    const f4* vi4 = (const f4*)(vim + b * K + lane * 8);
    f4 va0 = vr4[0], va1 = vr4[1], vb0 = vi4[0], vb1 = vi4[1];
    float xs[8];
    xs[0] = va0.x * va0.x + vb0.x * vb0.x;
    xs[1] = va0.y * va0.y + vb0.y * vb0.y;
    xs[2] = va0.z * va0.z + vb0.z * vb0.z;
    xs[3] = va0.w * va0.w + vb0.w * vb0.w;
    xs[4] = va1.x * va1.x + vb1.x * vb1.x;
    xs[5] = va1.y * va1.y + vb1.y * vb1.y;
    xs[6] = va1.z * va1.z + vb1.z * vb1.z;
    xs[7] = va1.w * va1.w + vb1.w * vb1.w;

    float s[8];
    s[0] = r0.x * r0.x + i0.x * i0.x;
    s[1] = r0.y * r0.y + i0.y * i0.y;
    s[2] = r0.z * r0.z + i0.z * i0.z;
    s[3] = r0.w * r0.w + i0.w * i0.w;
    s[4] = r1.x * r1.x + i1.x * i1.x;
    s[5] = r1.y * r1.y + i1.y * i1.y;
    s[6] = r1.z * r1.z + i1.z * i1.z;
    s[7] = r1.w * r1.w + i1.w * i1.w;

    half8 h;
#pragma unroll
    for (int q = 0; q < 8; ++q) h[q] = (_Float16)s[q];
    *(half8*)(habs + base) = h;

    // fp32 diagonal |H_jj|^2: lane j>>3 holds it
    float cand = s[j & 7];
    float d2   = __shfl(cand, j >> 3, 64);
    float xsqj = __shfl(xs[j & 7], j >> 3, 64);
    if (lane == (j >> 3)) dabs2[b * K + j] = cand;

    // layer-1 cov dot
    float acc = s[0] * xs[0] + s[1] * xs[1] + s[2] * xs[2] + s[3] * xs[3] +
                s[4] * xs[4] + s[5] * xs[5] + s[6] * xs[6] + s[7] * xs[7];
#pragma unroll
    for (int off = 32; off; off >>= 1) acc += __shfl_xor(acc, off, 64);

    int bj = (int)(b * K) + j;
    float ulv;
    if (lane == 0) {
        float cov = acc + noise[bj];
        float A   = d2 * xsqj;
        float w   = cov / (cov - A);
        float sc  = d2 * w / cov;
        vt_out[bj] = make_float2(sc * vre[bj], sc * vim[bj]);
        ulv = A * w / (cov * cov);
    }
    ulv = __shfl(ulv, 0, 64);

    // transposed-matvec partial over the 16 rows, LDS combine, dense atomic
    __shared__ float part[16 * PS];
    float* pw = part + wv * PS + lane * 8;
#pragma unroll
    for (int q = 0; q < 8; ++q) pw[q] = s[q] * ulv;
    __syncthreads();

    if (tid < K) {
        float t = 0.f;
#pragma unroll
        for (int w = 0; w < 16; ++w) t += part[w * PS + tid];
        atomicAdd(&ul0[b * K + tid], t);
    }
}

// ---------------------------------------------------------------------------
// One kernel per layer l>=2 input side:
// Phase 0: recompute previous layer's tail for the WHOLE row b locally
//   (ul[l-1][b,:] is complete at kernel entry): mu/ula, ar/dl mix, CReLU,
//   rc recombine, power corr -> vloc/xsql in LDS; jc==0 blocks also write
//   the previous layer's output slice.
// Phase 1: cov row-dot + u/w algebra for this block's 16 rows (xsq from LDS),
//   vtilde -> vtcur.
// Phase 2: fragment-reuse transposed matvec, LDS combine, atomicAdd into
//   dense ulcur. habs fp16 read once per layer; no ulpart, no k_fin.
// Grid: B*32 = 2048 blocks x 256.
// ---------------------------------------------------------------------------
__global__ __launch_bounds__(256) void k_layerA(const half_t* __restrict__ habs,
                                                const float* __restrict__ noise,
                                                const float* __restrict__ dabs2,
                                                const float* __restrict__ mp,
                                                const float* __restrict__ ar_re,
                                                const float* __restrict__ ar_im,
                                                const float* __restrict__ dl_re,
                                                const float* __restrict__ dl_im,
                                                const float* __restrict__ rc_re,
                                                const float* __restrict__ rc_im,
                                                const float* __restrict__ ulprev,
                                                const float2* __restrict__ vtprev,
                                                float* __restrict__ ulcur,
                                                float2* __restrict__ vtcur,
                                                float* __restrict__ outp) {
    int tid  = threadIdx.x;
    int lane = tid & 63;
    int wv   = tid >> 6;
    int b    = blockIdx.x >> 5;
    int jc   = blockIdx.x & 31;

    __shared__ float  xsql[K];
    __shared__ float2 vloc[K];
    __shared__ float  uls[16];
    __shared__ float  part[4 * PS];

    // ---- phase 0: previous-layer tail for the whole row b ----
#pragma unroll
    for (int e = 0; e < 2; ++e) {
        int c  = tid * 2 + e;
        int bc = b * K + c;
        float  ul = ulprev[bc];
        float2 vt = vtprev[bc];
        float  p  = mp[bc];
        float avt = sqrtf(vt.x * vt.x + vt.y * vt.y);
        float mu  = fmaxf(avt / sqrtf(p) - ul, 0.f);
        float inv = 1.f / (ul + mu);
        float ax = 0.f, ay = 0.f;
#pragma unroll
        for (int cc = 0; cc < C; ++cc) {
            float gre = ar_re[cc] * inv + dl_re[cc];
            float gim = ar_im[cc] * inv + dl_im[cc];
            float zre = fmaxf(vt.x * gre - vt.y * gim, 0.f);
            float zim = fmaxf(vt.x * gim + vt.y * gre, 0.f);
            ax += zre * rc_re[cc] - zim * rc_im[cc];
            ay += zre * rc_im[cc] + zim * rc_re[cc];
        }
        float n2   = ax * ax + ay * ay;
        float corr = fminf(sqrtf(p / fmaxf(p, n2)), 1.f);
        ax *= corr; ay *= corr;
        vloc[c] = make_float2(ax, ay);
        xsql[c] = ax * ax + ay * ay;
        if (jc == 0) ((float2*)outp)[bc] = make_float2(ax, ay);
    }
    __syncthreads();

    // ---- phase 1: cov + u/w for this block's 16 rows ----
    int j0 = jc * 16 + wv * 4;
    f4 xa = *(f4*)&xsql[lane * 8];
    f4 xb = *(f4*)&xsql[lane * 8 + 4];

    half8 h[4];
    const half8* rp = (const half8*)(habs + ((size_t)b * K + j0) * K);
#pragma unroll
    for (int r = 0; r < 4; ++r) h[r] = rp[r * (K / 8) + lane];

    float rs[4];
#pragma unroll
    for (int r = 0; r < 4; ++r) {
        float acc = (float)h[r][0] * xa.x + (float)h[r][1] * xa.y +
                    (float)h[r][2] * xa.z + (float)h[r][3] * xa.w +
                    (float)h[r][4] * xb.x + (float)h[r][5] * xb.y +
                    (float)h[r][6] * xb.z + (float)h[r][7] * xb.w;
#pragma unroll
        for (int off = 32; off; off >>= 1) acc += __shfl_xor(acc, off, 64);
        rs[r] = acc;
    }

    if (lane < 4) {
        float rsv = (lane == 0) ? rs[0] : (lane == 1) ? rs[1]
                  : (lane == 2) ? rs[2] : rs[3];
        int j  = j0 + lane;
        int bj = b * K + j;
        float cov = rsv + noise[bj];
        float A   = dabs2[bj] * xsql[j];
        float w   = cov / (cov - A);
        float sc  = dabs2[bj] * w / cov;
        float2 vv = vloc[j];
        vtcur[bj] = make_float2(sc * vv.x, sc * vv.y);
        uls[wv * 4 + lane] = A * w / (cov * cov);
    }
    __syncthreads();

    // ---- phase 2: transposed matvec from register fragments ----
    float u0 = uls[wv * 4 + 0];
    float u1 = uls[wv * 4 + 1];
    float u2 = uls[wv * 4 + 2];
    float u3 = uls[wv * 4 + 3];
    float* pw = part + wv * PS + lane * 8;
#pragma unroll
    for (int q = 0; q < 8; ++q) {
        pw[q] = (float)h[0][q] * u0 + (float)h[1][q] * u1 +
                (float)h[2][q] * u2 + (float)h[3][q] * u3;
    }
    __syncthreads();

    int c = tid * 2;
    float s0 = part[0 * PS + c]     + part[1 * PS + c]
             + part[2 * PS + c]     + part[3 * PS + c];
    float s1 = part[0 * PS + c + 1] + part[1 * PS + c + 1]
             + part[2 * PS + c + 1] + part[3 * PS + c + 1];
    atomicAdd(&ulcur[b * K + c],     s0);
    atomicAdd(&ulcur[b * K + c + 1], s1);
}

// ---------------------------------------------------------------------------
// Final tail: layer-5 output from ul[4] + vtilde.
// ---------------------------------------------------------------------------
__global__ __launch_bounds__(256) void k_fin_last(const float* __restrict__ ul4,
                                                  const float2* __restrict__ vt,
                                                  const float* __restrict__ mp,
                                                  const float* __restrict__ ar_re,
                                                  const float* __restrict__ ar_im,
                                                  const float* __restrict__ dl_re,
                                                  const float* __restrict__ dl_im,
                                                  const float* __restrict__ rc_re,
                                                  const float* __restrict__ rc_im,
                                                  float* __restrict__ outp) {
    int t = blockIdx.x * blockDim.x + threadIdx.x;
    float  ul = ul4[t];
    float2 vv = vt[t];
    float  p  = mp[t];
    float avt = sqrtf(vv.x * vv.x + vv.y * vv.y);
    float mu  = fmaxf(avt / sqrtf(p) - ul, 0.f);
    float inv = 1.f / (ul + mu);
    float ax = 0.f, ay = 0.f;
#pragma unroll
    for (int cc = 0; cc < C; ++cc) {
        float gre = ar_re[cc] * inv + dl_re[cc];
        float gim = ar_im[cc] * inv + dl_im[cc];
        float zre = fmaxf(vv.x * gre - vv.y * gim, 0.f);
        float zim = fmaxf(vv.x * gim + vv.y * gre, 0.f);
        ax += zre * rc_re[cc] - zim * rc_im[cc];
        ay += zre * rc_im[cc] + zim * rc_re[cc];
    }
    float n2   = ax * ax + ay * ay;
    float corr = fminf(sqrtf(p / fmaxf(p, n2)), 1.f);
    ((float2*)outp)[t] = make_float2(ax * corr, ay * corr);
}

// ---------------------------------------------------------------------------
extern "C" void kernel_launch(void* const* d_in, const int* in_sizes, int n_in,
                              void* d_out, int out_size, void* d_ws, size_t ws_size,
                              hipStream_t stream) {
    const float* hre   = (const float*)d_in[0];
    const float* him   = (const float*)d_in[1];
    const float* noise = (const float*)d_in[2];
    const float* mp    = (const float*)d_in[3];
    const float* vre   = (const float*)d_in[4];
    const float* vim   = (const float*)d_in[5];
    const float* ar_re = (const float*)d_in[6];
    const float* ar_im = (const float*)d_in[7];
    const float* dl_re = (const float*)d_in[8];
    const float* dl_im = (const float*)d_in[9];
    const float* rc_re = (const float*)d_in[10];
    const float* rc_im = (const float*)d_in[11];
    float* out = (float*)d_out;

    char*   ws    = (char*)d_ws;
    size_t  off   = 0;
    half_t* habs  = (half_t*)(ws + off); off += (size_t)BK * K * 2;  // 33.5 MB
    float*  dabs2 = (float*) (ws + off); off += (size_t)BK * 4;
    float2* vt_a  = (float2*)(ws + off); off += (size_t)BK * 8;
    float2* vt_b  = (float2*)(ws + off); off += (size_t)BK * 8;
    float*  ul    = (float*) (ws + off); off += (size_t)NL * BK * 4;  // 640 KB

    hipMemsetAsync(ul, 0, (size_t)NL * BK * 4, stream);

    // 2048 blocks x 1024 threads; block = 16 complete rows
    k_pre_l1<<<2048, 1024, 0, stream>>>(hre, him, vre, vim, noise,
                                        habs, dabs2, vt_a, ul);

    for (int l = 1; l < NL; ++l) {
        const float2* vtr = (l & 1) ? vt_a : vt_b;
        float2*       vtw = (l & 1) ? vt_b : vt_a;
        k_layerA<<<B * 32, 256, 0, stream>>>(habs, noise, dabs2, mp,
                                             ar_re, ar_im, dl_re, dl_im,
                                             rc_re, rc_im,
                                             ul + (size_t)(l - 1) * BK, vtr,
                                             ul + (size_t)l * BK, vtw,
                                             out + (size_t)(l - 1) * BK * 2);
    }
    k_fin_last<<<BK / 256, 256, 0, stream>>>(ul + (size_t)4 * BK, vt_a, mp,
                                             ar_re, ar_im, dl_re, dl_im,
                                             rc_re, rc_im,
                                             out + (size_t)4 * BK * 2);
}